// Round 1
// baseline (1245.889 us; speedup 1.0000x reference)
//
#include <hip/hip_runtime.h>
#include <math.h>

#define M_SPATIAL 2097152  // 128^3

__device__ __forceinline__ float wave_red(float v) {
#pragma unroll
  for (int o = 32; o > 0; o >>= 1) v += __shfl_down(v, o, 64);
  return v;
}

// ---------------------------------------------------------------------------
// Kernel A: g[v] = t ? 1e6 : 0 from y; accumulate CE + dice partial sums.
// acc layout (doubles): [0]=ce, [1+b]=sum p, [3+b]=sum p*t, [5+b]=sum t, [7]=dist
// ---------------------------------------------------------------------------
__global__ __launch_bounds__(256) void k_init(const float* __restrict__ outputs,
                                              const int* __restrict__ y,
                                              float* __restrict__ g,
                                              double* __restrict__ acc) {
  int v = blockIdx.x * 256 + threadIdx.x;   // 0..4194303; block never straddles b
  int b = v >> 21;
  int s = v & (M_SPATIAL - 1);
  int yv = y[v];
  float t = (yv == 1) ? 1.0f : 0.0f;
  g[v] = (yv == 1) ? 1.0e6f : 0.0f;
  float x = outputs[(size_t)(b * 2 + 1) * M_SPATIAL + s];  // channel 1
  float ce = fmaxf(x, 0.0f) - x * t + log1pf(expf(-fabsf(x)));
  float p = 1.0f / (1.0f + expf(-x));
  float pt = p * t;

  __shared__ float sm[4][4];
  float r0 = wave_red(ce), r1 = wave_red(p), r2 = wave_red(pt), r3 = wave_red(t);
  int lane = threadIdx.x & 63, w = threadIdx.x >> 6;
  if (lane == 0) { sm[w][0] = r0; sm[w][1] = r1; sm[w][2] = r2; sm[w][3] = r3; }
  __syncthreads();
  if (threadIdx.x == 0) {
    float a0 = 0, a1 = 0, a2 = 0, a3 = 0;
    for (int i = 0; i < 4; ++i) { a0 += sm[i][0]; a1 += sm[i][1]; a2 += sm[i][2]; a3 += sm[i][3]; }
    atomicAdd(&acc[0], (double)a0);
    atomicAdd(&acc[1 + b], (double)a1);
    atomicAdd(&acc[3 + b], (double)a2);
    atomicAdd(&acc[5 + b], (double)a3);
  }
}

// ---------------------------------------------------------------------------
// EDT pass along a strided axis (X: lineS=16384, Y: lineS=128).
// Tile: full line (128) x 64 contiguous z. Lanes traverse z => coalesced global,
// conflict-free LDS. j-outer loop, best[32] in registers: 3 VALU/term.
// All values are integers < 2^24 => exact fp32, identical to reference.
// ---------------------------------------------------------------------------
__global__ __launch_bounds__(256) void k_edt_strided(float* __restrict__ g,
                                                     int hiS, int loS, int lineS) {
  __shared__ float f[128 * 64];
  int tz = blockIdx.x & 1;
  int rest = blockIdx.x >> 1;            // (hi 0..1) * 128 + (lo 0..127)
  size_t base = (size_t)(rest >> 7) * (size_t)hiS +
                (size_t)(rest & 127) * (size_t)loS + (size_t)tz * 64;
  int zt = threadIdx.x & 63;
  int r0 = threadIdx.x >> 6;             // 0..3

#pragma unroll
  for (int k = 0; k < 32; ++k) {
    int i = r0 + k * 4;
    f[i * 64 + zt] = g[base + (size_t)i * lineS + zt];
  }
  __syncthreads();

  float best[32];
#pragma unroll
  for (int k = 0; k < 32; ++k) best[k] = 3.0e38f;
  float jf = 0.0f;
  float i0 = (float)r0;
  for (int j = 0; j < 128; ++j) {
    float vv = f[j * 64 + zt];
    float d0 = i0 - jf;
#pragma unroll
    for (int k = 0; k < 32; ++k) {
      float df = d0 + 4.0f * (float)k;           // exact small integer
      best[k] = fminf(best[k], fmaf(df, df, vv)); // exact: all < 2^24
    }
    jf += 1.0f;
  }

#pragma unroll
  for (int k = 0; k < 32; ++k) {
    int i = r0 + k * 4;
    g[base + (size_t)i * lineS + zt] = best[k];
  }
}

// ---------------------------------------------------------------------------
// EDT pass along contiguous z axis. Tile: 64 lines x 128 (one contiguous 32KiB
// chunk). Transpose in LDS (+pad) so lanes traverse the line index.
// ---------------------------------------------------------------------------
__global__ __launch_bounds__(256) void k_edt_z(float* __restrict__ g) {
  __shared__ float lds[128 * 65];        // ft[z*65 + l]; reused as ot[l*129 + z]
  size_t base = (size_t)blockIdx.x * 8192;
  int tid = threadIdx.x;

#pragma unroll
  for (int k = 0; k < 32; ++k) {
    int e = tid + k * 256;
    float val = g[base + e];
    lds[(e & 127) * 65 + (e >> 7)] = val;   // (z+l)%32 banks: conflict-free
  }
  __syncthreads();

  int l = tid & 63;
  int r0 = tid >> 6;
  float best[32];
#pragma unroll
  for (int k = 0; k < 32; ++k) best[k] = 3.0e38f;
  float jf = 0.0f;
  float i0 = (float)r0;
  for (int j = 0; j < 128; ++j) {
    float vv = lds[j * 65 + l];
    float d0 = i0 - jf;
#pragma unroll
    for (int k = 0; k < 32; ++k) {
      float df = d0 + 4.0f * (float)k;
      best[k] = fminf(best[k], fmaf(df, df, vv));
    }
    jf += 1.0f;
  }
  __syncthreads();
#pragma unroll
  for (int k = 0; k < 32; ++k)
    lds[l * 129 + (r0 + 4 * k)] = best[k];   // (l+i)%32 banks: conflict-free
  __syncthreads();
#pragma unroll
  for (int k = 0; k < 32; ++k) {
    int e = tid + k * 256;
    g[base + e] = lds[(e >> 7) * 129 + (e & 127)];
  }
}

// ---------------------------------------------------------------------------
// Dist kernel: sum |od - sqrt(g)| over foreground (g>0 <=> t==1).
// ---------------------------------------------------------------------------
__global__ __launch_bounds__(256) void k_dist(const float* __restrict__ od_full,
                                              const float* __restrict__ g,
                                              double* __restrict__ acc) {
  int v = blockIdx.x * 256 + threadIdx.x;
  int b = v >> 21;
  int s = v & (M_SPATIAL - 1);
  float gv = g[v];
  float dsum = 0.0f;
  if (gv > 0.0f) {
    float od = od_full[(size_t)(b * 2 + 1) * M_SPATIAL + s];
    dsum = fabsf(od - sqrtf(gv));
  }
  float r = wave_red(dsum);
  __shared__ float sm[4];
  int lane = threadIdx.x & 63, w = threadIdx.x >> 6;
  if (lane == 0) sm[w] = r;
  __syncthreads();
  if (threadIdx.x == 0) atomicAdd(&acc[7], (double)(sm[0] + sm[1] + sm[2] + sm[3]));
}

// ---------------------------------------------------------------------------
// Final combine into the scalar loss.
// ---------------------------------------------------------------------------
__global__ void k_final(const double* __restrict__ acc,
                        const float* __restrict__ wptr,
                        float* __restrict__ out) {
  double ce = acc[0] / 4194304.0;
  double dice0 = (2.0 * acc[3] + 1.0) / (acc[1] + acc[5] + 1.0);
  double dice1 = (2.0 * acc[4] + 1.0) / (acc[2] + acc[6] + 1.0);
  double ldice = 1.0 - 0.5 * (dice0 + dice1);
  double msum = acc[5] + acc[6];
  double ldist = (msum == 0.0) ? 0.0 : acc[7] / fmax(msum, 1e-12);
  out[0] = (float)(ce + ldice + (double)wptr[0] * ldist);
}

extern "C" void kernel_launch(void* const* d_in, const int* in_sizes, int n_in,
                              void* d_out, int out_size, void* d_ws, size_t ws_size,
                              hipStream_t stream) {
  const float* outputs      = (const float*)d_in[0];
  const float* outputs_dist = (const float*)d_in[1];
  const int*   y            = (const int*)d_in[2];
  const float* wptr         = (const float*)d_in[3];
  float* out = (float*)d_out;

  double* acc = (double*)d_ws;                    // 8 doubles
  float* g = (float*)((char*)d_ws + 256);         // 2*128^3 floats = 16 MiB

  hipMemsetAsync(d_ws, 0, 256, stream);           // zero accumulators (ws is poisoned)

  k_init<<<16384, 256, 0, stream>>>(outputs, y, g, acc);
  // Pass order matches reference: X, then Y, then Z (exact anyway — integers).
  k_edt_strided<<<512, 256, 0, stream>>>(g, M_SPATIAL, 128, 16384);   // X axis
  k_edt_strided<<<512, 256, 0, stream>>>(g, M_SPATIAL, 16384, 128);   // Y axis
  k_edt_z<<<512, 256, 0, stream>>>(g);                                 // Z axis
  k_dist<<<16384, 256, 0, stream>>>(outputs_dist, g, acc);
  k_final<<<1, 1, 0, stream>>>(acc, wptr, out);
}

// Round 2
// 280.089 us; speedup vs baseline: 4.4482x; 4.4482x over previous
//
#include <hip/hip_runtime.h>
#include <math.h>

#define M_SPATIAL 2097152  // 128^3
#define MV4 (M_SPATIAL / 4)

__device__ __forceinline__ float wave_redf(float v) {
#pragma unroll
  for (int o = 32; o > 0; o >>= 1) v += __shfl_down(v, o, 64);
  return v;
}
__device__ __forceinline__ double wave_redd(double v) {
#pragma unroll
  for (int o = 32; o > 0; o >>= 1) v += __shfl_down(v, o, 64);
  return v;
}

// part layout (doubles): [0..1023]=ce, [1024..]=p, [2048..]=pt, [3072..]=t, [4096..]=dist
// Blocks 0..511 cover b=0, 512..1023 cover b=1 (contiguous ranges).

// ---------------------------------------------------------------------------
// Kernel A: g = t ? 1e6 : 0; per-block partials for CE + dice sums. NO atomics.
// ---------------------------------------------------------------------------
__global__ __launch_bounds__(256) void k_init(const float4* __restrict__ outputs4,
                                              const int4* __restrict__ y4,
                                              float4* __restrict__ g4,
                                              double* __restrict__ part) {
  int blk = blockIdx.x;                 // 0..1023
  int base = blk * 1024;                // vec4 slots; 1024 slots/block
  int b = (blk >= 512) ? 1 : 0;
  const float4* xc = outputs4 + (size_t)(b * 2 + 1) * MV4;
  float ce = 0.f, ps = 0.f, pts = 0.f, tsum = 0.f;
#pragma unroll
  for (int k = 0; k < 4; ++k) {
    int v4 = base + (int)threadIdx.x + k * 256;
    int s4 = v4 & (MV4 - 1);
    int4 yv = y4[v4];
    float4 x = xc[s4];
    float4 gv;
#define ELEM(c, yc)                                                         \
    {                                                                       \
      float t = (yc == 1) ? 1.0f : 0.0f;                                    \
      gv.c = t * 1.0e6f;                                                    \
      float xx = x.c;                                                       \
      ce += fmaxf(xx, 0.0f) - xx * t + log1pf(expf(-fabsf(xx)));            \
      float p = 1.0f / (1.0f + expf(-xx));                                  \
      ps += p; pts += p * t; tsum += t;                                     \
    }
    ELEM(x, yv.x) ELEM(y, yv.y) ELEM(z, yv.z) ELEM(w, yv.w)
#undef ELEM
    g4[v4] = gv;
  }
  float r0 = wave_redf(ce), r1 = wave_redf(ps), r2 = wave_redf(pts), r3 = wave_redf(tsum);
  __shared__ float sm[4][4];
  int lane = threadIdx.x & 63, w = threadIdx.x >> 6;
  if (lane == 0) { sm[w][0] = r0; sm[w][1] = r1; sm[w][2] = r2; sm[w][3] = r3; }
  __syncthreads();
  if (threadIdx.x == 0) {
    part[blk]        = (double)(sm[0][0] + sm[1][0] + sm[2][0] + sm[3][0]);
    part[1024 + blk] = (double)(sm[0][1] + sm[1][1] + sm[2][1] + sm[3][1]);
    part[2048 + blk] = (double)(sm[0][2] + sm[1][2] + sm[2][2] + sm[3][2]);
    part[3072 + blk] = (double)(sm[0][3] + sm[1][3] + sm[2][3] + sm[3][3]);
  }
}

// ---------------------------------------------------------------------------
// EDT pass along a strided axis (X: lineS=16384, Y: lineS=128).
// All intermediate values are integers < 2^24 => exact fp32 == reference.
// ---------------------------------------------------------------------------
__global__ __launch_bounds__(256) void k_edt_strided(float* __restrict__ g,
                                                     int hiS, int loS, int lineS) {
  __shared__ float f[128 * 64];
  int tz = blockIdx.x & 1;
  int rest = blockIdx.x >> 1;
  size_t base = (size_t)(rest >> 7) * (size_t)hiS +
                (size_t)(rest & 127) * (size_t)loS + (size_t)tz * 64;
  int zt = threadIdx.x & 63;
  int r0 = threadIdx.x >> 6;

#pragma unroll
  for (int k = 0; k < 32; ++k) {
    int i = r0 + k * 4;
    f[i * 64 + zt] = g[base + (size_t)i * lineS + zt];
  }
  __syncthreads();

  float best[32];
#pragma unroll
  for (int k = 0; k < 32; ++k) best[k] = 3.0e38f;
  float jf = 0.0f;
  float i0 = (float)r0;
  for (int j = 0; j < 128; ++j) {
    float vv = f[j * 64 + zt];
    float d0 = i0 - jf;
#pragma unroll
    for (int k = 0; k < 32; ++k) {
      float df = d0 + 4.0f * (float)k;
      best[k] = fminf(best[k], fmaf(df, df, vv));
    }
    jf += 1.0f;
  }

#pragma unroll
  for (int k = 0; k < 32; ++k) {
    int i = r0 + k * 4;
    g[base + (size_t)i * lineS + zt] = best[k];
  }
}

// ---------------------------------------------------------------------------
// EDT pass along contiguous z: transpose in LDS (padded), transform, write back.
// ---------------------------------------------------------------------------
__global__ __launch_bounds__(256) void k_edt_z(float* __restrict__ g) {
  __shared__ float lds[128 * 65];
  size_t base = (size_t)blockIdx.x * 8192;
  int tid = threadIdx.x;

#pragma unroll
  for (int k = 0; k < 32; ++k) {
    int e = tid + k * 256;
    float val = g[base + e];
    lds[(e & 127) * 65 + (e >> 7)] = val;
  }
  __syncthreads();

  int l = tid & 63;
  int r0 = tid >> 6;
  float best[32];
#pragma unroll
  for (int k = 0; k < 32; ++k) best[k] = 3.0e38f;
  float jf = 0.0f;
  float i0 = (float)r0;
  for (int j = 0; j < 128; ++j) {
    float vv = lds[j * 65 + l];
    float d0 = i0 - jf;
#pragma unroll
    for (int k = 0; k < 32; ++k) {
      float df = d0 + 4.0f * (float)k;
      best[k] = fminf(best[k], fmaf(df, df, vv));
    }
    jf += 1.0f;
  }
  __syncthreads();
#pragma unroll
  for (int k = 0; k < 32; ++k)
    lds[l * 129 + (r0 + 4 * k)] = best[k];
  __syncthreads();
#pragma unroll
  for (int k = 0; k < 32; ++k) {
    int e = tid + k * 256;
    g[base + e] = lds[(e >> 7) * 129 + (e & 127)];
  }
}

// ---------------------------------------------------------------------------
// Dist kernel: per-block partial of sum |od - sqrt(g)| over foreground. NO atomics.
// ---------------------------------------------------------------------------
__global__ __launch_bounds__(256) void k_dist(const float4* __restrict__ od4,
                                              const float4* __restrict__ g4,
                                              double* __restrict__ part) {
  int blk = blockIdx.x;
  int base = blk * 1024;
  int b = (blk >= 512) ? 1 : 0;
  const float4* oc = od4 + (size_t)(b * 2 + 1) * MV4;
  float dsum = 0.f;
#pragma unroll
  for (int k = 0; k < 4; ++k) {
    int v4 = base + (int)threadIdx.x + k * 256;
    int s4 = v4 & (MV4 - 1);
    float4 gv = g4[v4];
    float4 od = oc[s4];
    if (gv.x > 0.f) dsum += fabsf(od.x - sqrtf(gv.x));
    if (gv.y > 0.f) dsum += fabsf(od.y - sqrtf(gv.y));
    if (gv.z > 0.f) dsum += fabsf(od.z - sqrtf(gv.z));
    if (gv.w > 0.f) dsum += fabsf(od.w - sqrtf(gv.w));
  }
  float r = wave_redf(dsum);
  __shared__ float sm[4];
  int lane = threadIdx.x & 63, w = threadIdx.x >> 6;
  if (lane == 0) sm[w] = r;
  __syncthreads();
  if (threadIdx.x == 0) part[4096 + blk] = (double)(sm[0] + sm[1] + sm[2] + sm[3]);
}

// ---------------------------------------------------------------------------
// Final: reduce 5x1024 partials in one block, combine to scalar loss.
// ---------------------------------------------------------------------------
__global__ __launch_bounds__(256) void k_final(const double* __restrict__ part,
                                               const float* __restrict__ wptr,
                                               float* __restrict__ out) {
  int i = threadIdx.x;
  double ce  = part[i] + part[i + 256] + part[i + 512] + part[i + 768];
  double p0  = part[1024 + i] + part[1024 + i + 256];
  double p1  = part[1536 + i] + part[1536 + i + 256];
  double pt0 = part[2048 + i] + part[2048 + i + 256];
  double pt1 = part[2560 + i] + part[2560 + i + 256];
  double t0  = part[3072 + i] + part[3072 + i + 256];
  double t1  = part[3584 + i] + part[3584 + i + 256];
  double ds  = part[4096 + i] + part[4096 + i + 256] + part[4096 + i + 512] + part[4096 + i + 768];

  ce = wave_redd(ce); p0 = wave_redd(p0); p1 = wave_redd(p1);
  pt0 = wave_redd(pt0); pt1 = wave_redd(pt1);
  t0 = wave_redd(t0); t1 = wave_redd(t1); ds = wave_redd(ds);

  __shared__ double sm[4][8];
  int lane = threadIdx.x & 63, w = threadIdx.x >> 6;
  if (lane == 0) {
    sm[w][0] = ce; sm[w][1] = p0; sm[w][2] = p1; sm[w][3] = pt0;
    sm[w][4] = pt1; sm[w][5] = t0; sm[w][6] = t1; sm[w][7] = ds;
  }
  __syncthreads();
  if (threadIdx.x == 0) {
    double a[8];
    for (int q = 0; q < 8; ++q) a[q] = sm[0][q] + sm[1][q] + sm[2][q] + sm[3][q];
    double cem = a[0] / 4194304.0;
    double dice0 = (2.0 * a[3] + 1.0) / (a[1] + a[5] + 1.0);
    double dice1 = (2.0 * a[4] + 1.0) / (a[2] + a[6] + 1.0);
    double ldice = 1.0 - 0.5 * (dice0 + dice1);
    double msum = a[5] + a[6];
    double ldist = (msum == 0.0) ? 0.0 : a[7] / fmax(msum, 1e-12);
    out[0] = (float)(cem + ldice + (double)wptr[0] * ldist);
  }
}

extern "C" void kernel_launch(void* const* d_in, const int* in_sizes, int n_in,
                              void* d_out, int out_size, void* d_ws, size_t ws_size,
                              hipStream_t stream) {
  const float* outputs      = (const float*)d_in[0];
  const float* outputs_dist = (const float*)d_in[1];
  const int*   y            = (const int*)d_in[2];
  const float* wptr         = (const float*)d_in[3];
  float* out = (float*)d_out;

  double* part = (double*)d_ws;                    // 5120 doubles = 40 KiB
  float* g = (float*)((char*)d_ws + 65536);        // 16 MiB scratch field

  k_init<<<1024, 256, 0, stream>>>((const float4*)outputs, (const int4*)y,
                                   (float4*)g, part);
  k_edt_strided<<<512, 256, 0, stream>>>(g, M_SPATIAL, 128, 16384);   // X axis
  k_edt_strided<<<512, 256, 0, stream>>>(g, M_SPATIAL, 16384, 128);   // Y axis
  k_edt_z<<<512, 256, 0, stream>>>(g);                                 // Z axis
  k_dist<<<1024, 256, 0, stream>>>((const float4*)outputs_dist,
                                   (const float4*)g, part);
  k_final<<<1, 256, 0, stream>>>(part, wptr, out);
}